// Round 1
// 1150.556 us; speedup vs baseline: 1.3148x; 1.3148x over previous
//
#include <hip/hip_runtime.h>
#include <math.h>

#define T 1024
#define D 768
#define H 12
#define HD 64
#define FF 3072
#define V 8192
#define EPS 1e-5f

typedef float float4e __attribute__((ext_vector_type(4)));
typedef short short8 __attribute__((ext_vector_type(8)));

__device__ __forceinline__ unsigned short f2bf(float f) {
    unsigned int u = __float_as_uint(f);
    unsigned int r = u + 0x7fffu + ((u >> 16) & 1u);
    return (unsigned short)(r >> 16);
}
__device__ __forceinline__ int imin(int a, int b) { return a < b ? a : b; }

#define GLL16(g, l)                                                                        \
    __builtin_amdgcn_global_load_lds((const __attribute__((address_space(1))) void*)(g),   \
                                     (__attribute__((address_space(3))) void*)(l), 16, 0, 0)

// ---------------- fp32 -> bf16 convert ----------------
__global__ void cvt_kernel(const float* __restrict__ in, unsigned short* __restrict__ out,
                           long long n) {
    long long i = ((long long)blockIdx.x * 256 + threadIdx.x) * 4;
    if (i + 3 < n) {
        float4e v = *(const float4e*)(in + i);
        out[i + 0] = f2bf(v[0]);
        out[i + 1] = f2bf(v[1]);
        out[i + 2] = f2bf(v[2]);
        out[i + 3] = f2bf(v[3]);
    }
}

// ---------------- LayerNorm over D=768 of (a+b), bf16 out ----------------
__global__ void ln_kernel(const float* __restrict__ a, const float* __restrict__ b,
                          const float* __restrict__ w, const float* __restrict__ bias,
                          unsigned short* __restrict__ out) {
    int t = blockIdx.x;
    int tid = threadIdx.x;
    __shared__ float red[256];
    float x[3];
    float s = 0.f;
#pragma unroll
    for (int k = 0; k < 3; k++) {
        int d = tid + k * 256;
        x[k] = a[t * D + d] + b[t * D + d];
        s += x[k];
    }
    red[tid] = s; __syncthreads();
    for (int o = 128; o > 0; o >>= 1) { if (tid < o) red[tid] += red[tid + o]; __syncthreads(); }
    float mu = red[0] / (float)D;
    __syncthreads();
    float sq = 0.f;
#pragma unroll
    for (int k = 0; k < 3; k++) { float dx = x[k] - mu; sq += dx * dx; }
    red[tid] = sq; __syncthreads();
    for (int o = 128; o > 0; o >>= 1) { if (tid < o) red[tid] += red[tid + o]; __syncthreads(); }
    float rstd = rsqrtf(red[0] / (float)D + EPS);
#pragma unroll
    for (int k = 0; k < 3; k++) {
        int d = tid + k * 256;
        out[t * D + d] = f2bf((x[k] - mu) * rstd * w[d] + bias[d]);
    }
}

// =====================================================================
// MFMA GEMM: C[M,N] = A[M,K] * B^T (+bias, +gelu). 128x128 tile, BK=32.
// AM: 0 = A fp32 (reg-stage + cvt), 1 = A bf16 (global_load_lds x16)
// BM: 0 = B fp32 [N,K], 1 = B bf16 [N,K] (global_load_lds), 2 = B fp32 [K,N]
// CB: store bf16. ATOM: atomicAdd fp32 (split-K / masked N). BIAS.
// grid.x = nTiles * kChunks, grid.y = M/128, grid.z = batch.
// =====================================================================
template <int AM, int BM, bool GELU_, bool CB, bool ATOM, bool BIAS>
__global__ __launch_bounds__(256, 2)
void mfma_gemm(const void* __restrict__ Av, const void* __restrict__ Bv,
               const float* __restrict__ bias, void* __restrict__ Cv,
               int M, int N, int K, int lda, int ldb, int ldc,
               long long sA, long long sB, long long sBias, long long sC,
               int nTiles, int kLen) {
    const int bz = blockIdx.z;
    const int nt = blockIdx.x % nTiles;
    const int kc = blockIdx.x / nTiles;
    const int m0 = blockIdx.y * 128;
    const int n0 = nt * 128;
    const int kBeg = kc * kLen, kEnd = kBeg + kLen;

    const int tid = threadIdx.x;
    const int lane = tid & 63;
    const int w = tid >> 6;
    const int wm = w >> 1, wn = w & 1;

    __shared__ __align__(16) unsigned short Asb[128 * 32];
    __shared__ __align__(16) unsigned short Bs[128 * 32];

    float4e acc[4][4];
#pragma unroll
    for (int i = 0; i < 4; i++)
#pragma unroll
        for (int j = 0; j < 4; j++) acc[i][j] = (float4e){0.f, 0.f, 0.f, 0.f};

    const int q = lane >> 4, r = lane & 15;

    for (int k0 = kBeg; k0 < kEnd; k0 += 32) {
        __syncthreads();
        // ---- stage A ----
        if constexpr (AM == 1) {
            const unsigned short* Ab = (const unsigned short*)Av + (long long)bz * sA;
            int rowA = lane >> 2, kg = (lane & 3) * 8;
#pragma unroll
            for (int s = 0; s < 2; s++) {
                int seg = w * 2 + s;
                int rs = seg * 16 + rowA;
                const unsigned short* g = Ab + (long long)(m0 + rs) * lda + k0 + kg;
                GLL16(g, &Asb[seg * 512]);
            }
        } else {
            const float* Af = (const float*)Av + (long long)bz * sA;
            int row = tid >> 1, half = tid & 1;
            const float4e* p = (const float4e*)(Af + (long long)(m0 + row) * lda + k0 + half * 16);
            float4e v0 = p[0], v1 = p[1], v2 = p[2], v3 = p[3];
            short8 s0, s1;
#pragma unroll
            for (int e = 0; e < 4; e++) {
                s0[e] = (short)f2bf(v0[e]); s0[e + 4] = (short)f2bf(v1[e]);
                s1[e] = (short)f2bf(v2[e]); s1[e + 4] = (short)f2bf(v3[e]);
            }
            *(short8*)&Asb[row * 32 + half * 16] = s0;
            *(short8*)&Asb[row * 32 + half * 16 + 8] = s1;
        }
        // ---- stage B ----
        if constexpr (BM == 1) {
            const unsigned short* Bb = (const unsigned short*)Bv + (long long)bz * sB;
            int rowA = lane >> 2, kg = (lane & 3) * 8;
#pragma unroll
            for (int s = 0; s < 2; s++) {
                int seg = w * 2 + s;
                int rs = imin(n0 + seg * 16 + rowA, N - 1);
                const unsigned short* g = Bb + (long long)rs * ldb + k0 + kg;
                GLL16(g, &Bs[seg * 512]);
            }
        } else if constexpr (BM == 0) {
            const float* Bf = (const float*)Bv + (long long)bz * sB;
            int row = tid >> 1, half = tid & 1;
            const float4e* p = (const float4e*)(Bf + (long long)(n0 + row) * ldb + k0 + half * 16);
            float4e v0 = p[0], v1 = p[1], v2 = p[2], v3 = p[3];
            short8 s0, s1;
#pragma unroll
            for (int e = 0; e < 4; e++) {
                s0[e] = (short)f2bf(v0[e]); s0[e + 4] = (short)f2bf(v1[e]);
                s1[e] = (short)f2bf(v2[e]); s1[e + 4] = (short)f2bf(v3[e]);
            }
            *(short8*)&Bs[row * 32 + half * 16] = s0;
            *(short8*)&Bs[row * 32 + half * 16 + 8] = s1;
        } else {  // BM == 2: fp32 [K,N], transpose-stage (N<=64 cols staged)
            const float* Bf = (const float*)Bv + (long long)bz * sB;
            int kk = tid >> 3, nn = (tid & 7) * 8;
            const float4e* p = (const float4e*)(Bf + (long long)(k0 + kk) * ldb + nn);
            float4e v0 = p[0], v1 = p[1];
#pragma unroll
            for (int e = 0; e < 4; e++) {
                Bs[(nn + e) * 32 + kk] = f2bf(v0[e]);
                Bs[(nn + 4 + e) * 32 + kk] = f2bf(v1[e]);
            }
        }
        __syncthreads();
        // ---- fragments + MFMA ----
        short8 af[4], bfr[4];
#pragma unroll
        for (int i = 0; i < 4; i++)
            af[i] = *(const short8*)&Asb[(wm * 64 + i * 16 + r) * 32 + q * 8];
#pragma unroll
        for (int j = 0; j < 4; j++)
            bfr[j] = *(const short8*)&Bs[(wn * 64 + j * 16 + r) * 32 + q * 8];
#pragma unroll
        for (int i = 0; i < 4; i++)
#pragma unroll
            for (int j = 0; j < 4; j++)
                acc[i][j] = __builtin_amdgcn_mfma_f32_16x16x32_bf16(af[i], bfr[j], acc[i][j], 0, 0, 0);
    }

    // ---- epilogue ----
    float* Cf = (float*)Cv + (long long)bz * sC;
    unsigned short* Cb = (unsigned short*)Cv + (long long)bz * sC;
    if (BIAS) bias += (long long)bz * sBias;
#pragma unroll
    for (int j = 0; j < 4; j++) {
        int n = n0 + wn * 64 + j * 16 + r;
        if (n >= N) continue;
        float bj = BIAS ? bias[n] : 0.f;
#pragma unroll
        for (int i = 0; i < 4; i++) {
            int mb = m0 + wm * 64 + i * 16 + q * 4;
#pragma unroll
            for (int rr = 0; rr < 4; rr++) {
                float v2 = acc[i][j][rr] + bj;
                if (GELU_) v2 = 0.5f * v2 * (1.0f + erff(v2 * 0.70710678118654752f));
                long long idx = (long long)(mb + rr) * ldc + n;
                if (ATOM) atomicAdd(&Cf[idx], v2);
                else if (CB) Cb[idx] = f2bf(v2);
                else Cf[idx] = v2;
            }
        }
    }
}

// ---------------- v = v_fact (HxH) applied per position; bf16 V^T out [H,64,T] ----
__global__ void vmix_kernel(const float* __restrict__ xt, const float* __restrict__ vf,
                            unsigned short* __restrict__ vt) {
    int t = blockIdx.x, tid = threadIdx.x;
    __shared__ float f[144];
    if (tid < 144) f[tid] = vf[tid];
    __syncthreads();
#pragma unroll
    for (int k = 0; k < 3; k++) {
        int o = tid + k * 256;
        int i = o >> 6, d = o & 63;
        float acc = 0.f;
#pragma unroll
        for (int j = 0; j < 12; j++) acc += f[i * 12 + j] * xt[t * D + j * 64 + d];
        vt[((long long)(i * 64 + d) << 10) + t] = f2bf(acc);  // [H,HD,T] bf16
    }
}

// ---------------- MFMA flash attention with alibi ----------------
// qkb: bf16 [T][1536] (q | k per row). vtb: bf16 [H*64][T] (V transposed).
// One block = 64 q-rows x 1 head; 4 waves x 16 rows, no cross-wave sync.
// S = Q K^T via 16x16x32 MFMA (frags straight from L2-resident global).
// Online softmax in regs (C layout: col=lane&15, row=(lane>>4)*4+reg).
// P transposed via per-wave 2KB LDS bounce, PV via MFMA with B = V^T.
__global__ __launch_bounds__(256)
void attn_mfma_kernel(const unsigned short* __restrict__ qkb,
                      const unsigned short* __restrict__ vtb,
                      float* __restrict__ y) {
    const int h = blockIdx.y;
    const int q0 = blockIdx.x * 64;
    const int tid = threadIdx.x;
    const int w = tid >> 6, lane = tid & 63;
    const int r = lane & 15, qg = lane >> 4;
    const int rowbase = q0 + w * 16;

    __shared__ __align__(16) unsigned short Ps[4][16 * 64];

    short8 aq0, aq1;
    {
        const unsigned short* qrow = qkb + (long long)(rowbase + r) * 1536 + h * 64 + qg * 8;
        aq0 = *(const short8*)(qrow);
        aq1 = *(const short8*)(qrow + 32);
    }
    const float slope = (h < 8) ? exp2f(-(float)(h + 1)) : exp2f(-0.5f * (float)(h - 7));
    const float scale = 0.125f;

    float m[4], l[4];
    float4e o[4];
#pragma unroll
    for (int i = 0; i < 4; i++) {
        m[i] = -INFINITY; l[i] = 0.f;
        o[i] = (float4e){0.f, 0.f, 0.f, 0.f};
    }

    const int jmax = rowbase + 15;  // last row this wave owns (causal bound)
    for (int j0 = 0; j0 <= jmax; j0 += 64) {
        // ---- S = Q K^T (16 x 64 per wave) ----
        float4e s[4];
#pragma unroll
        for (int jt = 0; jt < 4; jt++) s[jt] = (float4e){0.f, 0.f, 0.f, 0.f};
#pragma unroll
        for (int jt = 0; jt < 4; jt++) {
            const unsigned short* krow =
                qkb + (long long)(j0 + jt * 16 + r) * 1536 + 768 + h * 64 + qg * 8;
            short8 bk0 = *(const short8*)(krow);
            short8 bk1 = *(const short8*)(krow + 32);
            s[jt] = __builtin_amdgcn_mfma_f32_16x16x32_bf16(aq0, bk0, s[jt], 0, 0, 0);
            s[jt] = __builtin_amdgcn_mfma_f32_16x16x32_bf16(aq1, bk1, s[jt], 0, 0, 0);
        }
        // ---- online softmax (rows spread over 16 lanes; shfl_xor 1/2/4/8) ----
#pragma unroll
        for (int reg = 0; reg < 4; reg++) {
            const int tq = rowbase + qg * 4 + reg;
            float pv[4];
            float best = -INFINITY;
#pragma unroll
            for (int jt = 0; jt < 4; jt++) {
                int j = j0 + jt * 16 + r;
                float sv = s[jt][reg] * scale + slope * (float)(j - tq);
                if (j > tq) sv = -INFINITY;
                pv[jt] = sv;
                best = fmaxf(best, sv);
            }
#pragma unroll
            for (int mk = 1; mk < 16; mk <<= 1) best = fmaxf(best, __shfl_xor(best, mk));
            float mn = fmaxf(m[reg], best);
            float f = expf(m[reg] - mn);  // first tile: exp(-inf)=0
            m[reg] = mn;
            float ls = 0.f;
#pragma unroll
            for (int jt = 0; jt < 4; jt++) {
                float p = expf(pv[jt] - mn);
                ls += p;
                Ps[w][(qg * 4 + reg) * 64 + jt * 16 + r] = f2bf(p);
            }
#pragma unroll
            for (int mk = 1; mk < 16; mk <<= 1) ls += __shfl_xor(ls, mk);
            l[reg] = l[reg] * f + ls;
            o[0][reg] *= f; o[1][reg] *= f; o[2][reg] *= f; o[3][reg] *= f;
        }
        // ---- PV: O += P @ V  (A = P from LDS, B = V^T from global) ----
        short8 ap0 = *(const short8*)&Ps[w][r * 64 + qg * 8];
        short8 ap1 = *(const short8*)&Ps[w][r * 64 + 32 + qg * 8];
#pragma unroll
        for (int dt = 0; dt < 4; dt++) {
            const unsigned short* vr =
                vtb + ((long long)(h * 64 + dt * 16 + r) << 10) + j0 + qg * 8;
            short8 bv0 = *(const short8*)(vr);
            short8 bv1 = *(const short8*)(vr + 32);
            o[dt] = __builtin_amdgcn_mfma_f32_16x16x32_bf16(ap0, bv0, o[dt], 0, 0, 0);
            o[dt] = __builtin_amdgcn_mfma_f32_16x16x32_bf16(ap1, bv1, o[dt], 0, 0, 0);
        }
    }
    // ---- epilogue: y[t, h*64+d] = O / l ----
#pragma unroll
    for (int reg = 0; reg < 4; reg++) {
        float inv = 1.0f / l[reg];
        int t = rowbase + qg * 4 + reg;
#pragma unroll
        for (int dt = 0; dt < 4; dt++)
            y[(long long)t * D + h * 64 + dt * 16 + r] = o[dt][reg] * inv;
    }
}

// ---------------- out_fact mix + residual -> xt_new ----------
__global__ void outmix_kernel(const float* __restrict__ xt, const float* __restrict__ y,
                              const float* __restrict__ of, float* __restrict__ out) {
    int t = blockIdx.x, tid = threadIdx.x;
    __shared__ float f[144];
    if (tid < 144) f[tid] = of[tid];
    __syncthreads();
#pragma unroll
    for (int k = 0; k < 3; k++) {
        int o = tid + k * 256;
        int i = o >> 6, d = o & 63;
        float acc = 0.f;
#pragma unroll
        for (int j = 0; j < 12; j++) acc += f[i * 12 + j] * y[t * D + j * 64 + d];
        out[t * D + o] = xt[t * D + o] + acc;
    }
}

// ---------------- per-head LN over HD=64 of (hproj + proj_b); fp32 out ------
__global__ void headln_kernel(const float* __restrict__ in, const float* __restrict__ pb,
                              const float* __restrict__ w, const float* __restrict__ b,
                              float* __restrict__ out) {
    int rrow = blockIdx.x;   // [0, H*T)
    int lane = threadIdx.x;  // 64
    int h = rrow >> 10;
    float x = in[rrow * 64 + lane] + pb[h * 64 + lane];
    float s = x;
    for (int o = 32; o > 0; o >>= 1) s += __shfl_xor(s, o);
    float mu = s * (1.0f / 64.0f);
    float dx = x - mu;
    float qv = dx * dx;
    for (int o = 32; o > 0; o >>= 1) qv += __shfl_xor(qv, o);
    float rstd = rsqrtf(qv * (1.0f / 64.0f) + EPS);
    out[rrow * 64 + lane] = dx * rstd * w[h * 64 + lane] + b[h * 64 + lane];
}

// ---------------- row softmax over V=8192, in place, single pass in regs ----
__global__ void softmax_kernel(float* __restrict__ p) {
    long long row = blockIdx.x;
    float4e* x = (float4e*)(p + row * V);
    const int tid = threadIdx.x;
    const int w = tid >> 6;
    __shared__ float red[8];
    float4e v[8];
    float lm = -INFINITY;
#pragma unroll
    for (int k = 0; k < 8; k++) {
        v[k] = x[tid + k * 256];
        lm = fmaxf(lm, fmaxf(fmaxf(v[k][0], v[k][1]), fmaxf(v[k][2], v[k][3])));
    }
#pragma unroll
    for (int mk = 1; mk < 64; mk <<= 1) lm = fmaxf(lm, __shfl_xor(lm, mk));
    if ((tid & 63) == 0) red[w] = lm;
    __syncthreads();
    float m = fmaxf(fmaxf(red[0], red[1]), fmaxf(red[2], red[3]));
    float ls = 0.f;
#pragma unroll
    for (int k = 0; k < 8; k++) {
#pragma unroll
        for (int e = 0; e < 4; e++) { v[k][e] = expf(v[k][e] - m); ls += v[k][e]; }
    }
#pragma unroll
    for (int mk = 1; mk < 64; mk <<= 1) ls += __shfl_xor(ls, mk);
    if ((tid & 63) == 0) red[4 + w] = ls;
    __syncthreads();
    float inv = 1.0f / (red[4] + red[5] + red[6] + red[7]);
#pragma unroll
    for (int k = 0; k < 8; k++) {
        v[k][0] *= inv; v[k][1] *= inv; v[k][2] *= inv; v[k][3] *= inv;
        x[tid + k * 256] = v[k];
    }
}

// ---------------- loss (mean sq diff) + xe_new ----------
__global__ void loss_xe_kernel(const float* __restrict__ xhat, const float* __restrict__ xrec,
                               const float* __restrict__ xe, float* __restrict__ out_xe,
                               float* __restrict__ loss) {
    int i = blockIdx.x * 256 + threadIdx.x;
    float a = xhat[i], r = xrec[i];
    float df = a - r;
    int h = i >> 16;
    int t = (i >> 6) & 1023;
    int dd = i & 63;
    int oe = t * D + h * 64 + dd;
    out_xe[oe] = xe[oe] + r;
    __shared__ float red[256];
    red[threadIdx.x] = df * df; __syncthreads();
    for (int o = 128; o > 0; o >>= 1) { if (threadIdx.x < o) red[threadIdx.x] += red[threadIdx.x + o]; __syncthreads(); }
    if (threadIdx.x == 0) atomicAdd(loss, red[0] * (1.0f / 786432.0f));
}

extern "C" void kernel_launch(void* const* d_in, const int* in_sizes, int n_in,
                              void* d_out, int out_size, void* d_ws, size_t ws_size,
                              hipStream_t stream) {
    const float* xt = (const float*)d_in[0];
    const float* xe = (const float*)d_in[1];
    const float* ln1_w = (const float*)d_in[2];
    const float* ln1_b = (const float*)d_in[3];
    const float* qk_w = (const float*)d_in[4];
    const float* qk_b = (const float*)d_in[5];
    const float* v_fact = (const float*)d_in[6];
    const float* out_fact = (const float*)d_in[7];
    const float* ln2_w = (const float*)d_in[8];
    const float* ln2_b = (const float*)d_in[9];
    const float* fc_w = (const float*)d_in[10];
    const float* fc_b = (const float*)d_in[11];
    const float* proj_w = (const float*)d_in[12];
    const float* proj_b = (const float*)d_in[13];
    const float* dln_w = (const float*)d_in[14];
    const float* dln_b = (const float*)d_in[15];
    const float* dict_emb = (const float*)d_in[16];

    float* out_xt = (float*)d_out;
    float* out_xe = out_xt + (long long)T * D;
    float* out_dw = out_xe + (long long)T * D;               // [H,T,V] fp32, 100663296 floats
    float* out_loss = out_dw + (long long)H * T * V;

    // Scratch inside the (dead-until-logits) dict_weights region.
    unsigned short* hbuf = (unsigned short*)out_dw;          // [H,T,FF] bf16 = 18874368 floats
    float* sc = out_dw + 18874368;
    unsigned short* fc_wb   = (unsigned short*)(sc);                       // 14155776 f
    unsigned short* qk_wb   = (unsigned short*)(sc + 14155776);            //   589824 f
    unsigned short* proj_wb = (unsigned short*)(sc + 14155776 + 589824);   //  1179648 f
    unsigned short* xnormb  = (unsigned short*)(sc + 15925248);            //   393216 f
    unsigned short* x2b     = (unsigned short*)(sc + 16318464);            //   393216 f
    float* qkbuf = sc + 16711680;                                          //  1572864 f (used as bf16)
    float* vbuf  = sc + 18284544;                                          //   786432 f (used as bf16)
    float* ybuf  = sc + 19070976;                                          //   786432 f
    float* hproj = sc + 19857408;                                          //   786432 f
    float* xhat = (float*)d_ws;                              // 786432 f
    float* xrec = xhat + 786432;                             // 786432 f

    hipMemsetAsync(out_loss, 0, sizeof(float), stream);
    hipMemsetAsync(hproj, 0, 786432 * sizeof(float), stream);
    hipMemsetAsync(xrec, 0, 786432 * sizeof(float), stream);

    // weight converts
    cvt_kernel<<<27648, 256, 0, stream>>>(fc_w, fc_wb, 28311552LL);
    cvt_kernel<<<1152, 256, 0, stream>>>(qk_w, qk_wb, 1179648LL);
    cvt_kernel<<<2304, 256, 0, stream>>>(proj_w, proj_wb, 2359296LL);

    // 1) ln1(xt+xe) -> bf16
    ln_kernel<<<T, 256, 0, stream>>>(xt, xe, ln1_w, ln1_b, xnormb);
    // 2) v mix -> bf16 V^T [H,64,T]
    vmix_kernel<<<T, 256, 0, stream>>>(xt, v_fact, (unsigned short*)vbuf);
    // 3) qk = xnorm @ qk_w^T + qk_b  -> bf16 [1024,1536]
    mfma_gemm<1, 1, false, true, false, true><<<dim3(12, 8, 1), 256, 0, stream>>>(
        xnormb, qk_wb, qk_b, qkbuf, 1024, 1536, 768, 768, 768, 1536,
        0, 0, 0, 0, 12, 768);
    // 4) MFMA flash attention
    attn_mfma_kernel<<<dim3(16, 12), 256, 0, stream>>>(
        (const unsigned short*)qkbuf, (const unsigned short*)vbuf, ybuf);
    // 5) xt_new
    outmix_kernel<<<T, 256, 0, stream>>>(xt, ybuf, out_fact, out_xt);
    // 6) ln2 -> bf16
    ln_kernel<<<T, 256, 0, stream>>>(out_xt, xe, ln2_w, ln2_b, x2b);
    // 7) h = gelu(x2 @ fc_w^T + fc_b) -> bf16  [H,T,FF]
    mfma_gemm<1, 1, true, true, false, true><<<dim3(24, 8, 12), 256, 0, stream>>>(
        x2b, fc_wb, fc_b, hbuf, 1024, 3072, 768, 768, 768, 3072,
        0, (long long)FF * D, FF, (long long)T * FF, 24, 768);
    // 8) hproj = h @ proj_w^T (split-K=2, atomic)  [H,T,64]
    mfma_gemm<1, 1, false, false, true, false><<<dim3(2, 8, 12), 256, 0, stream>>>(
        hbuf, proj_wb, nullptr, hproj, 1024, 64, 3072, 3072, 3072, 64,
        (long long)T * FF, (long long)HD * FF, 0, (long long)T * HD, 1, 1536);
    // 9) x_hat = LN(hproj + proj_b)
    headln_kernel<<<H * T, 64, 0, stream>>>(hproj, proj_b, dln_w, dln_b, xhat);
    // 10) logits = x_hat @ dict_emb^T  [H,T,V]
    mfma_gemm<0, 0, false, false, false, false><<<dim3(64, 8, 12), 256, 0, stream>>>(
        xhat, dict_emb, nullptr, out_dw, 1024, 8192, 64, 64, 64, 8192,
        (long long)T * HD, (long long)V * HD, 0, (long long)T * V, 64, 64);
    // 11) softmax in place (single pass, regs)
    softmax_kernel<<<H * T, 256, 0, stream>>>(out_dw);
    // 12) x_recon = probs @ dict_emb (split-K=4, atomic)  [H,T,64]
    mfma_gemm<0, 2, false, false, true, false><<<dim3(4, 8, 12), 256, 0, stream>>>(
        out_dw, dict_emb, nullptr, xrec, 1024, 64, 8192, 8192, 64, 64,
        (long long)T * V, (long long)V * HD, 0, (long long)T * HD, 1, 2048);
    // 13) loss + xe_new
    loss_xe_kernel<<<(H * T * HD) / 256, 256, 0, stream>>>(xhat, xrec, xe, out_xe, out_loss);
}